// Round 13
// baseline (173.553 us; speedup 1.0000x reference)
//
#include <hip/hip_runtime.h>
#include <math.h>

// Problem constants (match reference)
#define BATCH 1024
#define NV    64      // N_VARS
#define MC    256     // M_CLAUSES
#define KD    12      // K_DIM
#define PI_F  3.14159265358979323846f

// Compact permuted C layout (floats, per m-split copy):
//   rows: 64 x 64. Row q = Gram row of 1-based var v = (q+1)%64+1 (0-based
//     target jv = (q+1)&63), cols {jv, jv-1, jv-2} (wrapped) PRE-ZEROED.
//   Within-row position perm(j0) = (j0&7)*8 + (j0>>3): lane group jgx reads a
//     CONTIGUOUS 8-float slice (j0 === jgx mod 8) = 2 ds_read_b128.
//   c0N[64]  at C0OFF : c0N[q]   = C[v][0]
//   DgA[64]  at DGAOFF: DgA[v-1] = C[v][prev1(v)]  -> readlane i gives C[i][i-1]
//   DgB[64]  at DGBOFF: DgB[v-1] = C[v][prev2(v)]  -> readlane i gives C[i][i-2]
#define C0OFF  4096
#define DGAOFF 4160
#define DGBOFF 4224
#define CBUF   4288

typedef float f2  __attribute__((ext_vector_type(2)));
typedef float v4f __attribute__((ext_vector_type(4)));
typedef __attribute__((address_space(3))) float lds_f;

// inline functions, NOT macros: braced f2 literals contain commas (r8 lesson).
__device__ __forceinline__ f2 bc2(float x) { f2 y; y.x = x; y.y = x; return y; }
__device__ __forceinline__ f2 fma2(f2 a, f2 b, f2 c) {
  return __builtin_elementwise_fma(a, b, c);
}

// ---- DPP add helpers (bound_ctrl=true, old=0 -> GCNDPPCombine-fusable) ----
// 0xB1 quad xor1 (bit0), 0x4E quad xor2 (bit1), 0x128 row_ror:8 == xor8
// within a 16-row (bit3, exact), 0x124 row_ror:4 (valid xor4 stand-in for the
// n2 staircase: operand uniform over bits {0,1,3}), 0x142 row_bcast15,
// 0x143 row_bcast31.
template <int CTRL>
__device__ __forceinline__ float dpp_addf(float x) {
  int y = __builtin_amdgcn_update_dpp(0, __float_as_int(x), CTRL, 0xF, 0xF, true);
  return x + __int_as_float(y);
}
__device__ __forceinline__ float readlane63(float x) {
  return __int_as_float(__builtin_amdgcn_readlane(__float_as_int(x), 63));
}
__device__ __forceinline__ float rlane(float x, int i) {
  return __int_as_float(__builtin_amdgcn_readlane(__float_as_int(x), i));
}

// Async LDS read: volatile pins the ISSUE point; counted s_waitcnt carries the
// consume-side ordering through REGISTER deps ("+v" on the slots).
template <int IMM>
__device__ __forceinline__ void dsr(v4f& d, unsigned base) {
  asm volatile("ds_read_b128 %0, %1 offset:%2" : "=v"(d) : "v"(base), "i"(IMM));
}

// ---- Kernel 1: Gram rows (permuted, pre-zeroed cols) + c0/dgA/dgB tables ----
__global__ void compute_C_kernel(const float* __restrict__ S,
                                 const float* __restrict__ w,
                                 float* __restrict__ Cg, int nsplit) {
  const int q = blockIdx.x;
  const int mc = blockIdx.y;
  const int j = threadIdx.x;  // column 0..64 (1-based vars; 0 = e0 row)
  if (j > NV) return;
  const int v = (q + 1) % 64 + 1;
  const int mlen = MC / nsplit;
  const int m0 = mc * mlen;
  float a0 = 0.f, a1 = 0.f, a2 = 0.f, a3 = 0.f;
  for (int m = m0; m < m0 + mlen; m += 4) {
    const float w0 = w[m], w1 = w[m + 1], w2 = w[m + 2], w3 = w[m + 3];
    a0 = fmaf(S[(m + 0) * (NV + 1) + v] * w0 * w0, S[(m + 0) * (NV + 1) + j], a0);
    a1 = fmaf(S[(m + 1) * (NV + 1) + v] * w1 * w1, S[(m + 1) * (NV + 1) + j], a1);
    a2 = fmaf(S[(m + 2) * (NV + 1) + v] * w2 * w2, S[(m + 2) * (NV + 1) + j], a2);
    a3 = fmaf(S[(m + 3) * (NV + 1) + v] * w3 * w3, S[(m + 3) * (NV + 1) + j], a3);
  }
  const float acc = (a0 + a1) + (a2 + a3);
  float* buf = Cg + mc * CBUF;
  const int p1 = (v == 1) ? 64 : (v - 1);
  const int p2 = (v == 1) ? 63 : (v == 2) ? 64 : (v - 2);
  if (j == 0) buf[C0OFF + q] = acc;
  if (j == p1) buf[DGAOFF + (v - 1)] = acc;
  if (j == p2) buf[DGBOFF + (v - 1)] = acc;
  if (j > 0) {
    const int j0 = j - 1;  // 0-based var column
    const float st = (j == v || j == p1 || j == p2) ? 0.f : acc;
    buf[q * 64 + (j0 & 7) * 8 + (j0 >> 3)] = st;  // permuted position
  }
}

// ---- Kernel 2: J=8 lane-split, 2 waves/SIMD (round-13 change) --------------
// Block = 512 thr = 8 waves = 8 batches; grid = 128 blocks -> 1 block/CU on
// 128 CUs, waves placed 2 per SIMD. Each SIMD round-robins TWO independent
// batch-chains: one wave's dependency/hazard/waitcnt stalls (~70% of wall at
// 1 wave/SIMD; r12 showed wall is stall-dominated, not slot-dominated) are
// filled by the other wave's ready instructions. True issue is 2 cy/instr
// (SIMD-32, m07), so two waves' demand still fits the issue budget; expected
// binder shifts to the LDS pipe (8 waves x 2 b128/step) or exec occupancy.
// Per-wave code identical to r11 (best measured) + r12's eps-seed.
__global__ __launch_bounds__(512, 1) void mixing_kernel(
    const float* __restrict__ z, const float* __restrict__ r,
    const float* __restrict__ Cg, const int* __restrict__ max_iter_p,
    float* __restrict__ out, int nsplit) {
  __shared__ __align__(16) float Ls[CBUF];  // 17152 B, shared by 8 waves

  const int t = threadIdx.x;
  const int l = t & 63;
  const int jgx = (l & 3) | ((l >> 1) & 4);          // lane bits 0,1,3
  const int kl = ((l >> 2) & 1) | ((l >> 3) & 6);    // lane bits 2,4,5
  const int b = blockIdx.x * 8 + (t >> 6);
  const int max_iter = max_iter_p[0];

  // stage (and m-split-reduce) compact C into LDS
  {
    const float4* src = (const float4*)Cg;
    float4* dst = (float4*)Ls;
    for (int idx = t; idx < CBUF / 4; idx += 512) {
      float4 a = src[idx];
      for (int u = 1; u < nsplit; ++u) {
        const float4 p = src[u * (CBUF / 4) + idx];
        a.x += p.x; a.y += p.y; a.z += p.z; a.w += p.w;
      }
      dst[idx] = a;
    }
  }

  const float my_e0 = (kl == 0) ? 1.f : 0.f;

  // ---- init: V[j][k] = -cos(pi z_j) [k=0] + sin(pi z_j) * rp_hat[k] ----
  f2 Vv[8];
  #pragma unroll
  for (int m = 0; m < 8; ++m) {
    const int j0 = jgx + 8 * m;
    const float zv = z[b * NV + j0];
    f2 rp = bc2(0.f);
    if (kl < 6) rp = *(const f2*)&r[(b * NV + j0) * KD + 2 * kl];
    if (kl == 0) rp.x = 0.f;  // k=0 excluded from r_perp
    float ssp = fmaf(rp.x, rp.x, rp.y * rp.y);
    ssp += __shfl_xor(ssp, 4, 64);    // k-bit 2
    ssp += __shfl_xor(ssp, 16, 64);   // k-bit 4
    ssp += __shfl_xor(ssp, 32, 64);   // k-bit 5
    const float inv = 1.f / fmaxf(sqrtf(ssp), 1e-8f);
    const float sn = __builtin_amdgcn_sinf(0.5f * zv);  // sin(pi*z)
    const float cs = __builtin_amdgcn_cosf(0.5f * zv);  // cos(pi*z)
    const float si = sn * inv;
    Vv[m].x = (kl == 0) ? -cs : si * rp.x;
    Vv[m].y = si * rp.y;
  }

  __syncthreads();

  // lane-distributed tables: lane x holds c0N[x], DgA[x], DgB[x]
  const float t0v = Ls[C0OFF + l];
  const float t1v = Ls[DGAOFF + l];
  const float t2v = Ls[DGBOFF + l];

  f2 P, vp1, vp2;

  // ---- prologue: Q for var 0 from row 63; vp1/vp2 = V_init[63/62] ----
  {
    const v4f cA = *(const v4f*)&Ls[63 * 64 + jgx * 8];
    const v4f cB = *(const v4f*)&Ls[63 * 64 + jgx * 8 + 4];
    f2 q = bc2(cA.x) * Vv[0];
    q = fma2(bc2(cA.y), Vv[1], q);
    q = fma2(bc2(cA.z), Vv[2], q);
    q = fma2(bc2(cA.w), Vv[3], q);
    q = fma2(bc2(cB.x), Vv[4], q);
    q = fma2(bc2(cB.y), Vv[5], q);
    q = fma2(bc2(cB.z), Vv[6], q);
    q = fma2(bc2(cB.w), Vv[7], q);
    q.x = dpp_addf<0xB1>(q.x);  q.y = dpp_addf<0xB1>(q.y);
    q.x = dpp_addf<0x4E>(q.x);  q.y = dpp_addf<0x4E>(q.y);
    q.x = dpp_addf<0x128>(q.x); q.y = dpp_addf<0x128>(q.y);
    q.x = fmaf(my_e0, Ls[C0OFF + 63], q.x);
    P = q;
    // j0=63 -> jgx=7 (lane bits 0,1,3 = 1); j0=62 -> jgx=6 (bits 1,3 = 1)
    vp1.x = __shfl(Vv[7].x, (l & 0x34) | 0x0B, 64);
    vp1.y = __shfl(Vv[7].y, (l & 0x34) | 0x0B, 64);
    vp2.x = __shfl(Vv[7].x, (l & 0x34) | 0x0A, 64);
    vp2.y = __shfl(Vv[7].y, (l & 0x34) | 0x0A, 64);
  }

  // LDS byte base for this lane's 32B row slice
  const unsigned lbase = (unsigned)(unsigned long long)(lds_f*)&Ls[jgx * 8];

  v4f Rb[8][2];  // 8-row ring (64 steps % 8 == 0 -> periodic slots)

#define PFROW(R) \
  dsr<((((R) & 63) * 256) + 0)>(Rb[(R) & 7][0], lbase); \
  dsr<((((R) & 63) * 256) + 16)>(Rb[(R) & 7][1], lbase);

// One wait per QUAD of steps: outstanding before wait = rows I..I+5 (12
// reads); lgkmcnt(4) retires the oldest 8 = rows I..I+3. Register deps on the
// four consumed slots order the consumers; everything else schedules freely.
#define WAITR4(I) \
  asm volatile("s_waitcnt lgkmcnt(4)" \
               : "+v"(Rb[(I) & 7][0]), "+v"(Rb[(I) & 7][1]), \
                 "+v"(Rb[((I) + 1) & 7][0]), "+v"(Rb[((I) + 1) & 7][1]), \
                 "+v"(Rb[((I) + 2) & 7][0]), "+v"(Rb[((I) + 2) & 7][1]), \
                 "+v"(Rb[((I) + 3) & 7][0]), "+v"(Rb[((I) + 3) & 7][1]));

#define STEPC(I) { \
  constexpr int i_ = (I); \
  constexpr int sl_ = i_ & 7; \
  constexpr int j0w_ = (i_ + 63) & 63; \
  constexpr int m_ = j0w_ >> 3; \
  constexpr int jgo_ = j0w_ & 7; \
  const float da_ = rlane(t1v, i_); \
  const float db_ = rlane(t2v, i_); \
  const float c0_ = rlane(t0v, i_); \
  /* chain head: the true recurrence (packed) */ \
  f2 g_ = fma2(bc2(da_), vp1, fma2(bc2(db_), vp2, P)); \
  /* eps seed in the local partial replaces fmax(n2,1e-16): summed guard */ \
  /* ~1.6e-16 across the 8 kl slots -- identical at fp32 precision (r12). */ \
  float t_ = fmaf(g_.x, g_.x, fmaf(g_.y, g_.y, 2e-17f)); \
  const v4f ceA = Rb[sl_][0], ceB = Rb[sl_][1]; \
  /* products: TWO independent 4-deep chains (qa over Vv[0..3], qb [4..7]) */ \
  f2 qa_ = bc2(ceA.x) * Vv[0]; \
  f2 qb_ = bc2(ceB.x) * Vv[4]; \
  qa_ = fma2(bc2(ceA.y), Vv[1], qa_); \
  qb_ = fma2(bc2(ceB.y), Vv[5], qb_); \
  t_ = dpp_addf<0x124>(t_);            /* xor4 (valid: uniform over jg) */ \
  qa_ = fma2(bc2(ceA.z), Vv[2], qa_); \
  qb_ = fma2(bc2(ceB.z), Vv[6], qb_); \
  t_ = dpp_addf<0x142>(t_);            /* row1+=row0, row3+=row2 */ \
  qa_ = fma2(bc2(ceA.w), Vv[3], qa_); \
  qb_ = fma2(bc2(ceB.w), Vv[7], qb_); \
  t_ = dpp_addf<0x143>(t_);            /* lane63 = total */ \
  f2 q_ = qa_ + qb_; \
  const float n2_ = readlane63(t_); \
  const float inv_ = __builtin_amdgcn_rsqf(n2_); \
  q_.x = dpp_addf<0xB1>(q_.x);  q_.y = dpp_addf<0xB1>(q_.y); \
  const f2 vn_ = g_ * bc2(-inv_); \
  q_.x = dpp_addf<0x4E>(q_.x);  q_.y = dpp_addf<0x4E>(q_.y); \
  q_.x = dpp_addf<0x128>(q_.x); q_.y = dpp_addf<0x128>(q_.y); \
  q_.x = fmaf(my_e0, c0_, q_.x); \
  /* delayed writeback of u_{i-1} (held in vp1) */ \
  Vv[m_].x = (jgx == jgo_) ? vp1.x : Vv[m_].x; \
  Vv[m_].y = (jgx == jgo_) ? vp1.y : Vv[m_].y; \
  /* rotate carried state (renamed by unroll) */ \
  vp2 = vp1; vp1 = vn_; P = q_; \
}

// Region: wait, 4 steps (compiler-schedulable as one window), then prefetch
// rows I+6..I+9 (slot WAR with steps I, I+1 resolved by volatile asm order).
#define QUAD(I) { WAITR4(I) \
                  STEPC(I) STEPC((I) + 1) STEPC((I) + 2) STEPC((I) + 3) \
                  PFROW((I) + 6) PFROW((I) + 7) PFROW((I) + 8) PFROW((I) + 9) }

#define Q16(N) QUAD(N) QUAD((N) + 4) QUAD((N) + 8) QUAD((N) + 12)

  // drain prologue LDS traffic so lgkm counts are ours alone
  asm volatile("s_waitcnt lgkmcnt(0)" ::: "memory");
  PFROW(0) PFROW(1) PFROW(2) PFROW(3) PFROW(4) PFROW(5)  // 12 reads in flight

  #pragma unroll 1
  for (int it = 0; it < max_iter; ++it) {
    Q16(0) Q16(16) Q16(32) Q16(48)
  }

  // final pending writeback: u_63 in vp1 -> j0=63 (jgx==7, m=7)
  Vv[7].x = (jgx == 7) ? vp1.x : Vv[7].x;
  Vv[7].y = (jgx == 7) ? vp1.y : Vv[7].y;

  // ---- epilogue: transpose k=0 slice via LDS (rows dead), coalesced out ----
  // 8 wave regions x 64 floats = [0,4096) -- fits in the dead row area.
  asm volatile("s_waitcnt lgkmcnt(0)" ::: "memory");  // retire ring tail reads
  __syncthreads();
  {
    float* Lw = Ls + (t >> 6) * 64;
    if (kl == 0) {  // k=0 lives in Vv[m].x of k-slot-0 lanes
      #pragma unroll
      for (int m = 0; m < 8; ++m) Lw[jgx + 8 * m] = Vv[m].x;
    }
    __builtin_amdgcn_s_waitcnt(0);  // lgkm drain (same-wave store->load)
    float cv = -Lw[l];
    cv = fminf(fmaxf(cv, -1.f + 1e-6f), 1.f - 1e-6f);
    out[b * NV + l] = acosf(cv) * (1.f / PI_F);
  }
}

extern "C" void kernel_launch(void* const* d_in, const int* in_sizes, int n_in,
                              void* d_out, int out_size, void* d_ws, size_t ws_size,
                              hipStream_t stream) {
  const float* z = (const float*)d_in[0];
  const float* S = (const float*)d_in[1];
  const float* w = (const float*)d_in[2];
  const float* r = (const float*)d_in[3];
  const int* max_iter = (const int*)d_in[4];
  float* Cg = (float*)d_ws;

  const int nsplit = (ws_size >= (size_t)8 * CBUF * 4) ? 8
                   : (ws_size >= (size_t)4 * CBUF * 4) ? 4 : 1;
  compute_C_kernel<<<dim3(NV, nsplit), 128, 0, stream>>>(S, w, Cg, nsplit);
  mixing_kernel<<<BATCH / 8, 512, 0, stream>>>(z, r, Cg, max_iter,
                                               (float*)d_out, nsplit);
}

// Round 14
// 134.024 us; speedup vs baseline: 1.2949x; 1.2949x over previous
//
#include <hip/hip_runtime.h>
#include <math.h>

// Problem constants (match reference)
#define BATCH 1024
#define NV    64      // N_VARS
#define MC    256     // M_CLAUSES
#define KD    12      // K_DIM
#define PI_F  3.14159265358979323846f

// Compact permuted C layout (floats, per m-split copy):
//   rows: 64 x 64. Row q = Gram row of 1-based var v = (q+1)%64+1 (0-based
//     target jv = (q+1)&63), cols {jv, jv-1, jv-2} (wrapped) PRE-ZEROED.
//   Within-row position perm(j0) = (j0&7)*8 + (j0>>3): lane group jgx reads a
//     CONTIGUOUS 8-float slice (j0 === jgx mod 8) = 2 ds_read_b128.
//   c0N[64]  at C0OFF : c0N[q]   = C[v][0]
//   DgA[64]  at DGAOFF: DgA[v-1] = C[v][prev1(v)]  -> readlane i gives C[i][i-1]
//   DgB[64]  at DGBOFF: DgB[v-1] = C[v][prev2(v)]  -> readlane i gives C[i][i-2]
#define C0OFF  4096
#define DGAOFF 4160
#define DGBOFF 4224
#define CBUF   4288

typedef float f2  __attribute__((ext_vector_type(2)));
typedef float v4f __attribute__((ext_vector_type(4)));
typedef __attribute__((address_space(3))) float lds_f;

// inline functions, NOT macros: braced f2 literals contain commas (r8 lesson).
__device__ __forceinline__ f2 bc2(float x) { f2 y; y.x = x; y.y = x; return y; }
__device__ __forceinline__ f2 fma2(f2 a, f2 b, f2 c) {
  return __builtin_elementwise_fma(a, b, c);
}

// ---- DPP add helpers (bound_ctrl=true, old=0 -> GCNDPPCombine-fusable) ----
// 0xB1 quad xor1 (bit0), 0x4E quad xor2 (bit1), 0x128 row_ror:8 == xor8
// within a 16-row (bit3, exact), 0x124 row_ror:4 (valid xor4 stand-in for the
// n2 staircase: operand uniform over bits {0,1,3}), 0x142 row_bcast15,
// 0x143 row_bcast31.
template <int CTRL>
__device__ __forceinline__ float dpp_addf(float x) {
  int y = __builtin_amdgcn_update_dpp(0, __float_as_int(x), CTRL, 0xF, 0xF, true);
  return x + __int_as_float(y);
}
__device__ __forceinline__ float readlane63(float x) {
  return __int_as_float(__builtin_amdgcn_readlane(__float_as_int(x), 63));
}
__device__ __forceinline__ float rlane(float x, int i) {
  return __int_as_float(__builtin_amdgcn_readlane(__float_as_int(x), i));
}

// Async LDS read: volatile pins the ISSUE point; counted s_waitcnt carries the
// consume-side ordering through REGISTER deps ("+v" on the slots).
template <int IMM>
__device__ __forceinline__ void dsr(v4f& d, unsigned base) {
  asm volatile("ds_read_b128 %0, %1 offset:%2" : "=v"(d) : "v"(base), "i"(IMM));
}

// ---- Kernel 1: Gram rows (permuted, pre-zeroed cols) + c0/dgA/dgB tables ----
__global__ void compute_C_kernel(const float* __restrict__ S,
                                 const float* __restrict__ w,
                                 float* __restrict__ Cg, int nsplit) {
  const int q = blockIdx.x;
  const int mc = blockIdx.y;
  const int j = threadIdx.x;  // column 0..64 (1-based vars; 0 = e0 row)
  if (j > NV) return;
  const int v = (q + 1) % 64 + 1;
  const int mlen = MC / nsplit;
  const int m0 = mc * mlen;
  float a0 = 0.f, a1 = 0.f, a2 = 0.f, a3 = 0.f;
  for (int m = m0; m < m0 + mlen; m += 4) {
    const float w0 = w[m], w1 = w[m + 1], w2 = w[m + 2], w3 = w[m + 3];
    a0 = fmaf(S[(m + 0) * (NV + 1) + v] * w0 * w0, S[(m + 0) * (NV + 1) + j], a0);
    a1 = fmaf(S[(m + 1) * (NV + 1) + v] * w1 * w1, S[(m + 1) * (NV + 1) + j], a1);
    a2 = fmaf(S[(m + 2) * (NV + 1) + v] * w2 * w2, S[(m + 2) * (NV + 1) + j], a2);
    a3 = fmaf(S[(m + 3) * (NV + 1) + v] * w3 * w3, S[(m + 3) * (NV + 1) + j], a3);
  }
  const float acc = (a0 + a1) + (a2 + a3);
  float* buf = Cg + mc * CBUF;
  const int p1 = (v == 1) ? 64 : (v - 1);
  const int p2 = (v == 1) ? 63 : (v == 2) ? 64 : (v - 2);
  if (j == 0) buf[C0OFF + q] = acc;
  if (j == p1) buf[DGAOFF + (v - 1)] = acc;
  if (j == p2) buf[DGBOFF + (v - 1)] = acc;
  if (j > 0) {
    const int j0 = j - 1;  // 0-based var column
    const float st = (j == v || j == p1 || j == p2) ? 0.f : acc;
    buf[q * 64 + (j0 & 7) * 8 + (j0 >> 3)] = st;  // permuted position
  }
}

// ---- Kernel 2: J=8 lane-split, triple-chain steps, 4-step regions ----------
// Best-measured configuration (r11 = 137.0 us total) + r12's eps-seed.
// Block = 256 thr = 4 waves = 4 batches -> 1024 waves on 1024 SIMDs: the
// unique full-occupancy mapping for 1024 serial batch-chains (r9: 2 batches/
// wave halves wave count, 0.63x; r13: 2 waves/SIMD covers half the CUs,
// 0.70x -- both measured worse; per-SIMD stall-fill gain exists (+41%, r13)
// but cannot be combined with full CU coverage at this batch count).
// Lane l: jgx = bit0|bit1|bit3 owns vars j0 === jgx (mod 8); kl = bit2|bit4|
// bit5 owns k-pair {2kl,2kl+1} (kl>=6 pad=0). Per step: g = P + da*vp1 +
// db*vp2 (pk) -> n2 staircase (ror4,bcast15,bcast31,readlane63; eps seeded
// in the local partial, no fmax) -> rsq -> vn (pk); Q_{i+1} = qa (Vv[0..3])
// || qb (Vv[4..7]) + merge + 3-hop jg butterfly (xor1,xor2,xor8) + e0;
// delayed writeback of u_{i-1}.
__global__ __launch_bounds__(256, 1) void mixing_kernel(
    const float* __restrict__ z, const float* __restrict__ r,
    const float* __restrict__ Cg, const int* __restrict__ max_iter_p,
    float* __restrict__ out, int nsplit) {
  __shared__ __align__(16) float Ls[CBUF];  // 17152 B

  const int t = threadIdx.x;
  const int l = t & 63;
  const int jgx = (l & 3) | ((l >> 1) & 4);          // lane bits 0,1,3
  const int kl = ((l >> 2) & 1) | ((l >> 3) & 6);    // lane bits 2,4,5
  const int b = blockIdx.x * 4 + (t >> 6);
  const int max_iter = max_iter_p[0];

  // stage (and m-split-reduce) compact C into LDS
  {
    const float4* src = (const float4*)Cg;
    float4* dst = (float4*)Ls;
    for (int idx = t; idx < CBUF / 4; idx += 256) {
      float4 a = src[idx];
      for (int u = 1; u < nsplit; ++u) {
        const float4 p = src[u * (CBUF / 4) + idx];
        a.x += p.x; a.y += p.y; a.z += p.z; a.w += p.w;
      }
      dst[idx] = a;
    }
  }

  const float my_e0 = (kl == 0) ? 1.f : 0.f;

  // ---- init: V[j][k] = -cos(pi z_j) [k=0] + sin(pi z_j) * rp_hat[k] ----
  f2 Vv[8];
  #pragma unroll
  for (int m = 0; m < 8; ++m) {
    const int j0 = jgx + 8 * m;
    const float zv = z[b * NV + j0];
    f2 rp = bc2(0.f);
    if (kl < 6) rp = *(const f2*)&r[(b * NV + j0) * KD + 2 * kl];
    if (kl == 0) rp.x = 0.f;  // k=0 excluded from r_perp
    float ssp = fmaf(rp.x, rp.x, rp.y * rp.y);
    ssp += __shfl_xor(ssp, 4, 64);    // k-bit 2
    ssp += __shfl_xor(ssp, 16, 64);   // k-bit 4
    ssp += __shfl_xor(ssp, 32, 64);   // k-bit 5
    const float inv = 1.f / fmaxf(sqrtf(ssp), 1e-8f);
    const float sn = __builtin_amdgcn_sinf(0.5f * zv);  // sin(pi*z)
    const float cs = __builtin_amdgcn_cosf(0.5f * zv);  // cos(pi*z)
    const float si = sn * inv;
    Vv[m].x = (kl == 0) ? -cs : si * rp.x;
    Vv[m].y = si * rp.y;
  }

  __syncthreads();

  // lane-distributed tables: lane x holds c0N[x], DgA[x], DgB[x]
  const float t0v = Ls[C0OFF + l];
  const float t1v = Ls[DGAOFF + l];
  const float t2v = Ls[DGBOFF + l];

  f2 P, vp1, vp2;

  // ---- prologue: Q for var 0 from row 63; vp1/vp2 = V_init[63/62] ----
  {
    const v4f cA = *(const v4f*)&Ls[63 * 64 + jgx * 8];
    const v4f cB = *(const v4f*)&Ls[63 * 64 + jgx * 8 + 4];
    f2 q = bc2(cA.x) * Vv[0];
    q = fma2(bc2(cA.y), Vv[1], q);
    q = fma2(bc2(cA.z), Vv[2], q);
    q = fma2(bc2(cA.w), Vv[3], q);
    q = fma2(bc2(cB.x), Vv[4], q);
    q = fma2(bc2(cB.y), Vv[5], q);
    q = fma2(bc2(cB.z), Vv[6], q);
    q = fma2(bc2(cB.w), Vv[7], q);
    q.x = dpp_addf<0xB1>(q.x);  q.y = dpp_addf<0xB1>(q.y);
    q.x = dpp_addf<0x4E>(q.x);  q.y = dpp_addf<0x4E>(q.y);
    q.x = dpp_addf<0x128>(q.x); q.y = dpp_addf<0x128>(q.y);
    q.x = fmaf(my_e0, Ls[C0OFF + 63], q.x);
    P = q;
    // j0=63 -> jgx=7 (lane bits 0,1,3 = 1); j0=62 -> jgx=6 (bits 1,3 = 1)
    vp1.x = __shfl(Vv[7].x, (l & 0x34) | 0x0B, 64);
    vp1.y = __shfl(Vv[7].y, (l & 0x34) | 0x0B, 64);
    vp2.x = __shfl(Vv[7].x, (l & 0x34) | 0x0A, 64);
    vp2.y = __shfl(Vv[7].y, (l & 0x34) | 0x0A, 64);
  }

  // LDS byte base for this lane's 32B row slice
  const unsigned lbase = (unsigned)(unsigned long long)(lds_f*)&Ls[jgx * 8];

  v4f Rb[8][2];  // 8-row ring (64 steps % 8 == 0 -> periodic slots)

#define PFROW(R) \
  dsr<((((R) & 63) * 256) + 0)>(Rb[(R) & 7][0], lbase); \
  dsr<((((R) & 63) * 256) + 16)>(Rb[(R) & 7][1], lbase);

// One wait per QUAD of steps: outstanding before wait = rows I..I+5 (12
// reads); lgkmcnt(4) retires the oldest 8 = rows I..I+3. Register deps on the
// four consumed slots order the consumers; everything else schedules freely.
#define WAITR4(I) \
  asm volatile("s_waitcnt lgkmcnt(4)" \
               : "+v"(Rb[(I) & 7][0]), "+v"(Rb[(I) & 7][1]), \
                 "+v"(Rb[((I) + 1) & 7][0]), "+v"(Rb[((I) + 1) & 7][1]), \
                 "+v"(Rb[((I) + 2) & 7][0]), "+v"(Rb[((I) + 2) & 7][1]), \
                 "+v"(Rb[((I) + 3) & 7][0]), "+v"(Rb[((I) + 3) & 7][1]));

#define STEPC(I) { \
  constexpr int i_ = (I); \
  constexpr int sl_ = i_ & 7; \
  constexpr int j0w_ = (i_ + 63) & 63; \
  constexpr int m_ = j0w_ >> 3; \
  constexpr int jgo_ = j0w_ & 7; \
  const float da_ = rlane(t1v, i_); \
  const float db_ = rlane(t2v, i_); \
  const float c0_ = rlane(t0v, i_); \
  /* chain head: the true recurrence (packed) */ \
  f2 g_ = fma2(bc2(da_), vp1, fma2(bc2(db_), vp2, P)); \
  /* eps seed in the local partial replaces fmax(n2,1e-16): summed guard */ \
  /* ~1.6e-16 across the 8 kl slots -- identical at fp32 precision (r12). */ \
  float t_ = fmaf(g_.x, g_.x, fmaf(g_.y, g_.y, 2e-17f)); \
  const v4f ceA = Rb[sl_][0], ceB = Rb[sl_][1]; \
  /* products: TWO independent 4-deep chains (qa over Vv[0..3], qb [4..7]) */ \
  f2 qa_ = bc2(ceA.x) * Vv[0]; \
  f2 qb_ = bc2(ceB.x) * Vv[4]; \
  qa_ = fma2(bc2(ceA.y), Vv[1], qa_); \
  qb_ = fma2(bc2(ceB.y), Vv[5], qb_); \
  t_ = dpp_addf<0x124>(t_);            /* xor4 (valid: uniform over jg) */ \
  qa_ = fma2(bc2(ceA.z), Vv[2], qa_); \
  qb_ = fma2(bc2(ceB.z), Vv[6], qb_); \
  t_ = dpp_addf<0x142>(t_);            /* row1+=row0, row3+=row2 */ \
  qa_ = fma2(bc2(ceA.w), Vv[3], qa_); \
  qb_ = fma2(bc2(ceB.w), Vv[7], qb_); \
  t_ = dpp_addf<0x143>(t_);            /* lane63 = total */ \
  f2 q_ = qa_ + qb_; \
  const float n2_ = readlane63(t_); \
  const float inv_ = __builtin_amdgcn_rsqf(n2_); \
  q_.x = dpp_addf<0xB1>(q_.x);  q_.y = dpp_addf<0xB1>(q_.y); \
  const f2 vn_ = g_ * bc2(-inv_); \
  q_.x = dpp_addf<0x4E>(q_.x);  q_.y = dpp_addf<0x4E>(q_.y); \
  q_.x = dpp_addf<0x128>(q_.x); q_.y = dpp_addf<0x128>(q_.y); \
  q_.x = fmaf(my_e0, c0_, q_.x); \
  /* delayed writeback of u_{i-1} (held in vp1) */ \
  Vv[m_].x = (jgx == jgo_) ? vp1.x : Vv[m_].x; \
  Vv[m_].y = (jgx == jgo_) ? vp1.y : Vv[m_].y; \
  /* rotate carried state (renamed by unroll) */ \
  vp2 = vp1; vp1 = vn_; P = q_; \
}

// Region: wait, 4 steps (compiler-schedulable as one window), then prefetch
// rows I+6..I+9 (slot WAR with steps I, I+1 resolved by volatile asm order).
#define QUAD(I) { WAITR4(I) \
                  STEPC(I) STEPC((I) + 1) STEPC((I) + 2) STEPC((I) + 3) \
                  PFROW((I) + 6) PFROW((I) + 7) PFROW((I) + 8) PFROW((I) + 9) }

#define Q16(N) QUAD(N) QUAD((N) + 4) QUAD((N) + 8) QUAD((N) + 12)

  // drain prologue LDS traffic so lgkm counts are ours alone
  asm volatile("s_waitcnt lgkmcnt(0)" ::: "memory");
  PFROW(0) PFROW(1) PFROW(2) PFROW(3) PFROW(4) PFROW(5)  // 12 reads in flight

  #pragma unroll 1
  for (int it = 0; it < max_iter; ++it) {
    Q16(0) Q16(16) Q16(32) Q16(48)
  }

  // final pending writeback: u_63 in vp1 -> j0=63 (jgx==7, m=7)
  Vv[7].x = (jgx == 7) ? vp1.x : Vv[7].x;
  Vv[7].y = (jgx == 7) ? vp1.y : Vv[7].y;

  // ---- epilogue: transpose k=0 slice via LDS (rows dead), coalesced out ----
  asm volatile("s_waitcnt lgkmcnt(0)" ::: "memory");  // retire ring tail reads
  __syncthreads();
  {
    float* Lw = Ls + (t >> 6) * 64;
    if (kl == 0) {  // k=0 lives in Vv[m].x of k-slot-0 lanes
      #pragma unroll
      for (int m = 0; m < 8; ++m) Lw[jgx + 8 * m] = Vv[m].x;
    }
    __builtin_amdgcn_s_waitcnt(0);  // lgkm drain (same-wave store->load)
    float cv = -Lw[l];
    cv = fminf(fmaxf(cv, -1.f + 1e-6f), 1.f - 1e-6f);
    out[b * NV + l] = acosf(cv) * (1.f / PI_F);
  }
}

extern "C" void kernel_launch(void* const* d_in, const int* in_sizes, int n_in,
                              void* d_out, int out_size, void* d_ws, size_t ws_size,
                              hipStream_t stream) {
  const float* z = (const float*)d_in[0];
  const float* S = (const float*)d_in[1];
  const float* w = (const float*)d_in[2];
  const float* r = (const float*)d_in[3];
  const int* max_iter = (const int*)d_in[4];
  float* Cg = (float*)d_ws;

  const int nsplit = (ws_size >= (size_t)8 * CBUF * 4) ? 8
                   : (ws_size >= (size_t)4 * CBUF * 4) ? 4 : 1;
  compute_C_kernel<<<dim3(NV, nsplit), 128, 0, stream>>>(S, w, Cg, nsplit);
  mixing_kernel<<<BATCH / 4, 256, 0, stream>>>(z, r, Cg, max_iter,
                                               (float*)d_out, nsplit);
}